// Round 1
// baseline (856.598 us; speedup 1.0000x reference)
//
#include <hip/hip_runtime.h>

#define T_TOKENS 16384
#define DM 1024      // d_model
#define DI 4096      // d_inner
#define NE 8
#define PAIRS 64     // sparse pair slots: p = lo*8+hi, lo<hi
#define CAP 16384    // max tokens per pair

typedef float f32x4 __attribute__((ext_vector_type(4)));
typedef __bf16 bf16x8 __attribute__((ext_vector_type(8)));

__device__ inline unsigned short f2b(float f) {
  union { float f; unsigned u; } v; v.f = f;
  unsigned r = v.u + 0x7FFFu + ((v.u >> 16) & 1u);   // round-to-nearest-even bf16
  return (unsigned short)(r >> 16);
}

// ---------------- gating: fp64 logits -> softmax scores, top-2 -> pair lists; also emit bf16 X
__global__ __launch_bounds__(256) void k_gating(
    const float* __restrict__ x, const float* __restrict__ gw, const float* __restrict__ gb,
    unsigned short* __restrict__ x16, float* __restrict__ scores,
    int* __restrict__ cnt, int* __restrict__ ptok)
{
  int wid  = (blockIdx.x * 256 + threadIdx.x) >> 6;   // one wave per token
  int lane = threadIdx.x & 63;
  if (wid >= T_TOKENS) return;
  const float* xr = x + (size_t)wid * DM;

  double acc[NE];
  #pragma unroll
  for (int e = 0; e < NE; e++) acc[e] = 0.0;

  #pragma unroll
  for (int u = 0; u < 4; u++) {
    int off = u * 256 + lane * 4;
    float4 xv = *(const float4*)(xr + off);
    ushort4 pk; pk.x = f2b(xv.x); pk.y = f2b(xv.y); pk.z = f2b(xv.z); pk.w = f2b(xv.w);
    *(ushort4*)(x16 + (size_t)wid * DM + off) = pk;
    #pragma unroll
    for (int e = 0; e < NE; e++) {
      float4 wv = *(const float4*)(gw + e * DM + off);
      acc[e] += (double)xv.x * wv.x + (double)xv.y * wv.y
              + (double)xv.z * wv.z + (double)xv.w * wv.w;
    }
  }
  #pragma unroll
  for (int e = 0; e < NE; e++) {
    double v = acc[e];
    #pragma unroll
    for (int s = 32; s > 0; s >>= 1) v += __shfl_xor(v, s, 64);
    acc[e] = v + (double)gb[e];
  }
  if (lane == 0) {
    double m = acc[0];
    for (int e = 1; e < NE; e++) if (acc[e] > m) m = acc[e];
    double ex[NE], sum = 0.0;
    for (int e = 0; e < NE; e++) { ex[e] = exp(acc[e] - m); sum += ex[e]; }
    double inv = 1.0 / sum;
    for (int e = 0; e < NE; e++) scores[(size_t)wid * NE + e] = (float)(ex[e] * inv);
    int e1 = 0; double b1 = acc[0];
    for (int e = 1; e < NE; e++) if (acc[e] > b1) { b1 = acc[e]; e1 = e; }
    int e2 = -1; double b2 = -1e300;
    for (int e = 0; e < NE; e++) if (e != e1 && acc[e] > b2) { b2 = acc[e]; e2 = e; }
    int lo = e1 < e2 ? e1 : e2, hi = e1 < e2 ? e2 : e1;
    int p = lo * 8 + hi;
    int pos = atomicAdd(&cnt[p], 1);
    ptok[p * CAP + pos] = wid;
  }
}

// ---------------- expert_w fp32 -> bf16
__global__ __launch_bounds__(256) void k_wconv(const float* __restrict__ w, unsigned short* __restrict__ w16) {
  size_t i = ((size_t)blockIdx.x * 256 + threadIdx.x) * 4;
  float4 v = *(const float4*)(w + i);
  ushort4 pk; pk.x = f2b(v.x); pk.y = f2b(v.y); pk.z = f2b(v.z); pk.w = f2b(v.w);
  *(ushort4*)(w16 + i) = pk;
}

// ---------------- tile scheduler: row-tiles of 128 per nonempty pair
__global__ void k_sched(const int* __restrict__ cnt, int* __restrict__ tiles, int* __restrict__ ntiles) {
  if (threadIdx.x == 0 && blockIdx.x == 0) {
    int n = 0;
    for (int p = 0; p < PAIRS; p++) {
      int c = cnt[p];
      for (int r = 0; r < c; r += 128) { tiles[2 * n] = p; tiles[2 * n + 1] = r; n++; }
    }
    *ntiles = n;
  }
}

// ---------------- grouped GEMM: per pair-tile, Y = X_gather @ (W_e1^T and W_e2^T) accumulated
__global__ __launch_bounds__(256) void k_gemm(
    const unsigned short* __restrict__ x16, const unsigned short* __restrict__ w16,
    const float* __restrict__ eb, const int* __restrict__ cnt,
    const int* __restrict__ ptok, const int* __restrict__ tiles, const int* __restrict__ ntiles,
    float* __restrict__ out)
{
  __shared__ unsigned short As[128 * 64];
  __shared__ unsigned short Bs[2][128 * 64];

  int tileIdx = blockIdx.y;
  if (tileIdx >= *ntiles) return;
  int p    = tiles[2 * tileIdx];
  int row0 = tiles[2 * tileIdx + 1];
  int e1 = p >> 3, e2 = p & 7;
  int c  = cnt[p];
  int nTile = blockIdx.x;           // 0..31 over d_inner
  int tid  = threadIdx.x;
  int lane = tid & 63;
  int wid  = tid >> 6;
  int waveM = wid >> 1, waveN = wid & 1;

  // staging map: thread covers rows tid>>3 + {0,32,64,96}, k-chunk (tid&7)*8 (16B each)
  int tok[4];
  #pragma unroll
  for (int i = 0; i < 4; i++) {
    int rg = row0 + (tid >> 3) + i * 32;
    if (rg > c - 1) rg = c - 1;                    // clamp to a valid token for dummy rows
    tok[i] = ptok[p * CAP + rg];
  }
  int kc = (tid & 7) * 8;

  f32x4 acc[4][4];
  #pragma unroll
  for (int i = 0; i < 4; i++)
    #pragma unroll
    for (int j = 0; j < 4; j++) acc[i][j] = {0.f, 0.f, 0.f, 0.f};

  const unsigned short* bb1 = w16 + ((size_t)e1 * DI + (size_t)nTile * 128) * DM;
  const unsigned short* bb2 = w16 + ((size_t)e2 * DI + (size_t)nTile * 128) * DM;

  for (int k0 = 0; k0 < DM; k0 += 64) {
    #pragma unroll
    for (int i = 0; i < 4; i++) {
      int r = (tid >> 3) + i * 32;
      __builtin_amdgcn_global_load_lds(
          (const __attribute__((address_space(1))) void*)(x16 + (size_t)tok[i] * DM + k0 + kc),
          (__attribute__((address_space(3))) void*)(&As[r * 64 + kc]), 16, 0, 0);
      __builtin_amdgcn_global_load_lds(
          (const __attribute__((address_space(1))) void*)(bb1 + (size_t)r * DM + k0 + kc),
          (__attribute__((address_space(3))) void*)(&Bs[0][r * 64 + kc]), 16, 0, 0);
      __builtin_amdgcn_global_load_lds(
          (const __attribute__((address_space(1))) void*)(bb2 + (size_t)r * DM + k0 + kc),
          (__attribute__((address_space(3))) void*)(&Bs[1][r * 64 + kc]), 16, 0, 0);
    }
    __syncthreads();
    #pragma unroll
    for (int kk = 0; kk < 2; kk++) {
      int ko = kk * 32 + (lane >> 4) * 8;
      bf16x8 af[4], bf0[4], bf1[4];
      #pragma unroll
      for (int mi = 0; mi < 4; mi++)
        af[mi] = *(const bf16x8*)&As[(waveM * 64 + mi * 16 + (lane & 15)) * 64 + ko];
      #pragma unroll
      for (int ni = 0; ni < 4; ni++) {
        bf0[ni] = *(const bf16x8*)&Bs[0][(waveN * 64 + ni * 16 + (lane & 15)) * 64 + ko];
        bf1[ni] = *(const bf16x8*)&Bs[1][(waveN * 64 + ni * 16 + (lane & 15)) * 64 + ko];
      }
      #pragma unroll
      for (int mi = 0; mi < 4; mi++)
        #pragma unroll
        for (int ni = 0; ni < 4; ni++) {
          acc[mi][ni] = __builtin_amdgcn_mfma_f32_16x16x32_bf16(af[mi], bf0[ni], acc[mi][ni], 0, 0, 0);
          acc[mi][ni] = __builtin_amdgcn_mfma_f32_16x16x32_bf16(af[mi], bf1[ni], acc[mi][ni], 0, 0, 0);
        }
    }
    __syncthreads();
  }

  // epilogue: out[tok][col] = 0.5*acc + 0.5*(b_e1+b_e2); C/D layout: col=lane&15, row=(lane>>4)*4+reg
  int colbase = nTile * 128 + waveN * 64;
  float bsum[4];
  #pragma unroll
  for (int ni = 0; ni < 4; ni++) {
    int col = colbase + ni * 16 + (lane & 15);
    bsum[ni] = 0.5f * (eb[e1 * DI + col] + eb[e2 * DI + col]);
  }
  #pragma unroll
  for (int mi = 0; mi < 4; mi++) {
    #pragma unroll
    for (int r2 = 0; r2 < 4; r2++) {
      int row = waveM * 64 + mi * 16 + (lane >> 4) * 4 + r2;
      int rg = row0 + row;
      if (rg < c) {
        int t = ptok[p * CAP + rg];
        float* orow = out + (size_t)t * DI + colbase;
        #pragma unroll
        for (int ni = 0; ni < 4; ni++)
          orow[ni * 16 + (lane & 15)] = 0.5f * acc[mi][ni][r2] + bsum[ni];
      }
    }
  }
}

// ---------------- per-expert unbiased variance of softmax scores
__global__ __launch_bounds__(256) void k_var(const float* __restrict__ scores, float* __restrict__ vout) {
  int e = blockIdx.x, tid = threadIdx.x;
  double s = 0.0, s2 = 0.0;
  for (int t = tid; t < T_TOKENS; t += 256) {
    double v = (double)scores[(size_t)t * NE + e];
    s += v; s2 += v * v;
  }
  __shared__ double ls[256], ls2[256];
  ls[tid] = s; ls2[tid] = s2; __syncthreads();
  for (int st = 128; st > 0; st >>= 1) {
    if (tid < st) { ls[tid] += ls[tid + st]; ls2[tid] += ls2[tid + st]; }
    __syncthreads();
  }
  if (tid == 0) {
    double mean = ls[0] / (double)T_TOKENS;
    vout[e] = (float)((ls2[0] - ls[0] * mean) / (double)(T_TOKENS - 1));
  }
}

extern "C" void kernel_launch(void* const* d_in, const int* in_sizes, int n_in,
                              void* d_out, int out_size, void* d_ws, size_t ws_size,
                              hipStream_t stream)
{
  const float* x  = (const float*)d_in[0];
  const float* gw = (const float*)d_in[1];
  const float* gb = (const float*)d_in[2];
  const float* ew = (const float*)d_in[3];
  const float* eb = (const float*)d_in[4];
  float* out = (float*)d_out;

  // workspace layout (~105.4 MB)
  char* ws = (char*)d_ws;
  unsigned short* x16 = (unsigned short*)ws;                    // 33,554,432 B
  unsigned short* w16 = (unsigned short*)(ws + 33554432);       // 67,108,864 B
  float* scores       = (float*)(ws + 100663296);               //    524,288 B
  int*   ptok         = (int*)(ws + 101187584);                 //  4,194,304 B
  int*   cnt          = (int*)(ws + 105381888);                 //        256 B
  int*   ntiles       = (int*)(ws + 105382144);                 //          4 B
  int*   tiles        = (int*)(ws + 105382160);                 //      1,280 B

  hipMemsetAsync(cnt, 0, PAIRS * sizeof(int), stream);
  k_gating<<<dim3(4096), dim3(256), 0, stream>>>(x, gw, gb, x16, scores, cnt, ptok);
  k_wconv <<<dim3(32768), dim3(256), 0, stream>>>(ew, w16);
  k_sched <<<dim3(1), dim3(64), 0, stream>>>(cnt, tiles, ntiles);
  k_gemm  <<<dim3(32, 160), dim3(256), 0, stream>>>(x16, w16, eb, cnt, ptok, tiles, ntiles, out);
  k_var   <<<dim3(8), dim3(256), 0, stream>>>(scores, out + 67108864);
}

// Round 2
// 828.964 us; speedup vs baseline: 1.0333x; 1.0333x over previous
//
#include <hip/hip_runtime.h>

#define T_TOKENS 16384
#define DM 1024      // d_model
#define DI 4096      // d_inner
#define NE 8
#define PAIRS 64     // sparse pair slots: p = lo*8+hi, lo<hi
#define CAP 16384    // max tokens per pair

typedef float f32x4 __attribute__((ext_vector_type(4)));
typedef __bf16 bf16x8 __attribute__((ext_vector_type(8)));

__device__ inline unsigned short f2b(float f) {
  union { float f; unsigned u; } v; v.f = f;
  unsigned r = v.u + 0x7FFFu + ((v.u >> 16) & 1u);   // round-to-nearest-even bf16
  return (unsigned short)(r >> 16);
}

// ---------------- gating: fp64 logits -> softmax scores, top-2 -> pair lists; also emit bf16 X
__global__ __launch_bounds__(256) void k_gating(
    const float* __restrict__ x, const float* __restrict__ gw, const float* __restrict__ gb,
    unsigned short* __restrict__ x16, float* __restrict__ scores,
    int* __restrict__ cnt, int* __restrict__ ptok)
{
  int wid  = (blockIdx.x * 256 + threadIdx.x) >> 6;   // one wave per token
  int lane = threadIdx.x & 63;
  if (wid >= T_TOKENS) return;
  const float* xr = x + (size_t)wid * DM;

  double acc[NE];
  #pragma unroll
  for (int e = 0; e < NE; e++) acc[e] = 0.0;

  #pragma unroll
  for (int u = 0; u < 4; u++) {
    int off = u * 256 + lane * 4;
    float4 xv = *(const float4*)(xr + off);
    ushort4 pk; pk.x = f2b(xv.x); pk.y = f2b(xv.y); pk.z = f2b(xv.z); pk.w = f2b(xv.w);
    *(ushort4*)(x16 + (size_t)wid * DM + off) = pk;
    #pragma unroll
    for (int e = 0; e < NE; e++) {
      float4 wv = *(const float4*)(gw + e * DM + off);
      acc[e] += (double)xv.x * wv.x + (double)xv.y * wv.y
              + (double)xv.z * wv.z + (double)xv.w * wv.w;
    }
  }
  #pragma unroll
  for (int e = 0; e < NE; e++) {
    double v = acc[e];
    #pragma unroll
    for (int s = 32; s > 0; s >>= 1) v += __shfl_xor(v, s, 64);
    acc[e] = v + (double)gb[e];
  }
  if (lane == 0) {
    double m = acc[0];
    for (int e = 1; e < NE; e++) if (acc[e] > m) m = acc[e];
    double ex[NE], sum = 0.0;
    for (int e = 0; e < NE; e++) { ex[e] = exp(acc[e] - m); sum += ex[e]; }
    double inv = 1.0 / sum;
    for (int e = 0; e < NE; e++) scores[(size_t)wid * NE + e] = (float)(ex[e] * inv);
    int e1 = 0; double b1 = acc[0];
    for (int e = 1; e < NE; e++) if (acc[e] > b1) { b1 = acc[e]; e1 = e; }
    int e2 = -1; double b2 = -1e300;
    for (int e = 0; e < NE; e++) if (e != e1 && acc[e] > b2) { b2 = acc[e]; e2 = e; }
    int lo = e1 < e2 ? e1 : e2, hi = e1 < e2 ? e2 : e1;
    int p = lo * 8 + hi;
    int pos = atomicAdd(&cnt[p], 1);
    ptok[p * CAP + pos] = wid;
  }
}

// ---------------- expert_w fp32 -> bf16 (8 floats/thread)
__global__ __launch_bounds__(256) void k_wconv(const float* __restrict__ w, unsigned short* __restrict__ w16) {
  size_t i = ((size_t)blockIdx.x * 256 + threadIdx.x) * 8;
  float4 a = *(const float4*)(w + i);
  float4 b = *(const float4*)(w + i + 4);
  ushort4 pa, pb;
  pa.x = f2b(a.x); pa.y = f2b(a.y); pa.z = f2b(a.z); pa.w = f2b(a.w);
  pb.x = f2b(b.x); pb.y = f2b(b.y); pb.z = f2b(b.z); pb.w = f2b(b.w);
  *(ushort4*)(w16 + i) = pa;
  *(ushort4*)(w16 + i + 4) = pb;
}

// ---------------- tile scheduler: wave-parallel scan over 64 pairs
__global__ void k_sched(const int* __restrict__ cnt, int* __restrict__ tiles, int* __restrict__ ntiles) {
  int p = threadIdx.x;            // 0..63, one wave
  int c = cnt[p];
  int nt = (c + 127) >> 7;
  int inc = nt;
  #pragma unroll
  for (int s = 1; s < 64; s <<= 1) {
    int v = __shfl_up(inc, s, 64);
    if (p >= s) inc += v;
  }
  int excl = inc - nt;
  for (int i = 0; i < nt; i++) { tiles[2 * (excl + i)] = p; tiles[2 * (excl + i) + 1] = i * 128; }
  if (p == 63) *ntiles = inc;
}

// ---------------- grouped GEMM: per pair-tile, Y = X_gather @ (W_e1^T and W_e2^T) accumulated
// LDS layout: row-major 128x64 shorts, but k-chunk (16B) index is XOR-swizzled by (row&7)
// at the GLOBAL source, so LDS[r][c] holds global chunk c^(r&7). This spreads MFMA fragment
// reads across all 32 banks (was 16-way conflict at stride 128B).
__global__ __launch_bounds__(256) void k_gemm(
    const unsigned short* __restrict__ x16, const unsigned short* __restrict__ w16,
    const float* __restrict__ eb, const int* __restrict__ cnt,
    const int* __restrict__ ptok, const int* __restrict__ tiles, const int* __restrict__ ntiles,
    float* __restrict__ out)
{
  __shared__ unsigned short As[128 * 64];
  __shared__ unsigned short Bs[2][128 * 64];

  int tileIdx = blockIdx.y;
  if (tileIdx >= *ntiles) return;
  int p    = tiles[2 * tileIdx];
  int row0 = tiles[2 * tileIdx + 1];
  int e1 = p >> 3, e2 = p & 7;
  int c  = cnt[p];
  int nTile = blockIdx.x;           // 0..31 over d_inner
  int tid  = threadIdx.x;
  int lane = tid & 63;
  int wid  = tid >> 6;
  int waveM = wid >> 1, waveN = wid & 1;

  // staging map: thread covers rows (tid>>3) + {0,32,64,96}; LDS chunk c = tid&7 (16B),
  // global source chunk = c ^ (r&7)  (bank-conflict swizzle; coalescing within 128B kept)
  int tok[4];
  #pragma unroll
  for (int i = 0; i < 4; i++) {
    int rg = row0 + (tid >> 3) + i * 32;
    if (rg > c - 1) rg = c - 1;                    // clamp to a valid token for dummy rows
    tok[i] = ptok[p * CAP + rg];
  }

  f32x4 acc[4][4];
  #pragma unroll
  for (int i = 0; i < 4; i++)
    #pragma unroll
    for (int j = 0; j < 4; j++) acc[i][j] = {0.f, 0.f, 0.f, 0.f};

  const unsigned short* bb1 = w16 + ((size_t)e1 * DI + (size_t)nTile * 128) * DM;
  const unsigned short* bb2 = w16 + ((size_t)e2 * DI + (size_t)nTile * 128) * DM;

  for (int k0 = 0; k0 < DM; k0 += 64) {
    #pragma unroll
    for (int i = 0; i < 4; i++) {
      int r  = (tid >> 3) + i * 32;
      int cS = tid & 7;                // LDS chunk slot (fixed by lane id)
      int kg = ((cS ^ (r & 7)) * 8);   // swizzled global k-chunk, in shorts
      __builtin_amdgcn_global_load_lds(
          (const __attribute__((address_space(1))) void*)(x16 + (size_t)tok[i] * DM + k0 + kg),
          (__attribute__((address_space(3))) void*)(&As[r * 64 + cS * 8]), 16, 0, 0);
      __builtin_amdgcn_global_load_lds(
          (const __attribute__((address_space(1))) void*)(bb1 + (size_t)r * DM + k0 + kg),
          (__attribute__((address_space(3))) void*)(&Bs[0][r * 64 + cS * 8]), 16, 0, 0);
      __builtin_amdgcn_global_load_lds(
          (const __attribute__((address_space(1))) void*)(bb2 + (size_t)r * DM + k0 + kg),
          (__attribute__((address_space(3))) void*)(&Bs[1][r * 64 + cS * 8]), 16, 0, 0);
    }
    __syncthreads();
    #pragma unroll
    for (int kk = 0; kk < 2; kk++) {
      int q  = lane >> 4;              // quarter
      int m  = lane & 15;
      int jg = kk * 4 + q;             // logical global k-chunk for this fragment
      bf16x8 af[4], bf0[4], bf1[4];
      #pragma unroll
      for (int mi = 0; mi < 4; mi++) {
        int R = waveM * 64 + mi * 16 + m;
        af[mi] = *(const bf16x8*)&As[R * 64 + ((jg ^ (R & 7)) * 8)];
      }
      #pragma unroll
      for (int ni = 0; ni < 4; ni++) {
        int R = waveN * 64 + ni * 16 + m;
        int o = R * 64 + ((jg ^ (R & 7)) * 8);
        bf0[ni] = *(const bf16x8*)&Bs[0][o];
        bf1[ni] = *(const bf16x8*)&Bs[1][o];
      }
      #pragma unroll
      for (int mi = 0; mi < 4; mi++)
        #pragma unroll
        for (int ni = 0; ni < 4; ni++) {
          acc[mi][ni] = __builtin_amdgcn_mfma_f32_16x16x32_bf16(af[mi], bf0[ni], acc[mi][ni], 0, 0, 0);
          acc[mi][ni] = __builtin_amdgcn_mfma_f32_16x16x32_bf16(af[mi], bf1[ni], acc[mi][ni], 0, 0, 0);
        }
    }
    __syncthreads();
  }

  // epilogue: out[tok][col] = 0.5*acc + 0.5*(b_e1+b_e2); C/D layout: col=lane&15, row=(lane>>4)*4+reg
  int colbase = nTile * 128 + waveN * 64;
  float bsum[4];
  #pragma unroll
  for (int ni = 0; ni < 4; ni++) {
    int col = colbase + ni * 16 + (lane & 15);
    bsum[ni] = 0.5f * (eb[e1 * DI + col] + eb[e2 * DI + col]);
  }
  #pragma unroll
  for (int mi = 0; mi < 4; mi++) {
    #pragma unroll
    for (int r2 = 0; r2 < 4; r2++) {
      int row = waveM * 64 + mi * 16 + (lane >> 4) * 4 + r2;
      int rg = row0 + row;
      if (rg < c) {
        int t = ptok[p * CAP + rg];
        float* orow = out + (size_t)t * DI + colbase;
        #pragma unroll
        for (int ni = 0; ni < 4; ni++)
          orow[ni * 16 + (lane & 15)] = 0.5f * acc[mi][ni][r2] + bsum[ni];
      }
    }
  }
}

// ---------------- per-expert unbiased variance of softmax scores
__global__ __launch_bounds__(256) void k_var(const float* __restrict__ scores, float* __restrict__ vout) {
  int e = blockIdx.x, tid = threadIdx.x;
  double s = 0.0, s2 = 0.0;
  for (int t = tid; t < T_TOKENS; t += 256) {
    double v = (double)scores[(size_t)t * NE + e];
    s += v; s2 += v * v;
  }
  __shared__ double ls[256], ls2[256];
  ls[tid] = s; ls2[tid] = s2; __syncthreads();
  for (int st = 128; st > 0; st >>= 1) {
    if (tid < st) { ls[tid] += ls[tid + st]; ls2[tid] += ls2[tid + st]; }
    __syncthreads();
  }
  if (tid == 0) {
    double mean = ls[0] / (double)T_TOKENS;
    vout[e] = (float)((ls2[0] - ls[0] * mean) / (double)(T_TOKENS - 1));
  }
}

extern "C" void kernel_launch(void* const* d_in, const int* in_sizes, int n_in,
                              void* d_out, int out_size, void* d_ws, size_t ws_size,
                              hipStream_t stream)
{
  const float* x  = (const float*)d_in[0];
  const float* gw = (const float*)d_in[1];
  const float* gb = (const float*)d_in[2];
  const float* ew = (const float*)d_in[3];
  const float* eb = (const float*)d_in[4];
  float* out = (float*)d_out;

  // workspace layout (~105.4 MB)
  char* ws = (char*)d_ws;
  unsigned short* x16 = (unsigned short*)ws;                    // 33,554,432 B
  unsigned short* w16 = (unsigned short*)(ws + 33554432);       // 67,108,864 B
  float* scores       = (float*)(ws + 100663296);               //    524,288 B
  int*   ptok         = (int*)(ws + 101187584);                 //  4,194,304 B
  int*   cnt          = (int*)(ws + 105381888);                 //        256 B
  int*   ntiles       = (int*)(ws + 105382144);                 //          4 B
  int*   tiles        = (int*)(ws + 105382160);                 //      1,280 B

  hipMemsetAsync(cnt, 0, PAIRS * sizeof(int), stream);
  k_gating<<<dim3(4096), dim3(256), 0, stream>>>(x, gw, gb, x16, scores, cnt, ptok);
  k_wconv <<<dim3(16384), dim3(256), 0, stream>>>(ew, w16);
  k_sched <<<dim3(1), dim3(64), 0, stream>>>(cnt, tiles, ntiles);
  k_gemm  <<<dim3(32, 160), dim3(256), 0, stream>>>(x16, w16, eb, cnt, ptok, tiles, ntiles, out);
  k_var   <<<dim3(8), dim3(256), 0, stream>>>(scores, out + 67108864);
}